// Round 2
// baseline (1729.922 us; speedup 1.0000x reference)
//
#include <hip/hip_runtime.h>
#include <stdint.h>
#include <math.h>

#define HID 64
#define DIN 128
#define DOUT 40
#define N_LAYERS 8

static inline int cdiv(int a, int b) { return (a + b - 1) / b; }

// ---------- edge-index layout detection (int32 vs int64 storage) ----------
__global__ void detect_i64(const uint32_t* __restrict__ ei, int* __restrict__ flag) {
    int t = threadIdx.x;                 // 64 threads
    uint32_t w = ei[2 * t + 1];          // upper words if int64, odd src entries if int32
    unsigned long long nz = __ballot(w != 0u);
    if (t == 0) *flag = (nz == 0ull) ? 1 : 0;
}

__device__ __forceinline__ int edge_src(const uint32_t* ei, int is64, int E, int e) {
    return is64 ? (int)ei[2 * e] : (int)ei[e];
}
__device__ __forceinline__ int edge_dst(const uint32_t* ei, int is64, int E, int e) {
    return is64 ? (int)ei[2 * (size_t)E + 2 * e] : (int)ei[(size_t)E + e];
}

// ---------- CSR construction ----------
__global__ void init_cnt(int* __restrict__ cnt, int n) {
    int v = blockIdx.x * blockDim.x + threadIdx.x;
    if (v < n) cnt[v] = 0;
}

__global__ void count_deg(const uint32_t* __restrict__ ei, const int* __restrict__ flag,
                          int* __restrict__ cnt, int E) {
    int e = blockIdx.x * blockDim.x + threadIdx.x;
    if (e >= E) return;
    int is64 = *flag;
    atomicAdd(&cnt[edge_dst(ei, is64, E, e)], 1);
}

__global__ void scan1(const int* __restrict__ cnt, int* __restrict__ row_start,
                      int* __restrict__ blocksum, int n) {
    __shared__ int sh[256];
    int t = threadIdx.x;
    int v = blockIdx.x * 256 + t;
    int val = (v < n) ? cnt[v] : 0;
    sh[t] = val;
    __syncthreads();
    for (int o = 1; o < 256; o <<= 1) {
        int y = (t >= o) ? sh[t - o] : 0;
        __syncthreads();
        sh[t] += y;
        __syncthreads();
    }
    if (v < n) row_start[v] = sh[t] - val;     // exclusive within block
    if (t == 255) blocksum[blockIdx.x] = sh[255];
}

__global__ void scan2(int* __restrict__ blocksum, int nb) {
    __shared__ int sh[512];
    int t = threadIdx.x;
    int val = (t < nb) ? blocksum[t] : 0;
    sh[t] = val;
    __syncthreads();
    for (int o = 1; o < 512; o <<= 1) {
        int y = (t >= o) ? sh[t - o] : 0;
        __syncthreads();
        sh[t] += y;
        __syncthreads();
    }
    if (t < nb) blocksum[t] = sh[t] - val;     // exclusive
}

__global__ void scan3(int* __restrict__ row_start, const int* __restrict__ blocksum,
                      int* __restrict__ cursor, int n) {
    int v = blockIdx.x * 256 + threadIdx.x;
    if (v < n) {
        row_start[v] += blocksum[v >> 8];
        cursor[v] = 0;
    }
}

__global__ void compute_dinv(const int* __restrict__ cnt, float* __restrict__ dinv, int n) {
    int v = blockIdx.x * blockDim.x + threadIdx.x;
    if (v < n) dinv[v] = rsqrtf((float)(cnt[v] + 1));   // +1 self loop
}

// weightless: only src index stored; dinv folded into node features instead
__global__ void scatter_edges(const uint32_t* __restrict__ ei, const int* __restrict__ flag,
                              const int* __restrict__ row_start, int* __restrict__ cursor,
                              int* __restrict__ csr_src, int E) {
    int e = blockIdx.x * blockDim.x + threadIdx.x;
    if (e >= E) return;
    int is64 = *flag;
    int s = edge_src(ei, is64, E, e);
    int d = edge_dst(ei, is64, E, e);
    int pos = row_start[d] + atomicAdd(&cursor[d], 1);
    csr_src[pos] = s;
}

// ---------- h0 = relu(x @ W1 + b1); hp = dinv * h0 ----------
// 4 waves per block; wave wv holds W1 k-chunk [32wv,32wv+32) column f in regs.
#define MLPIN_NB 8
__global__ void mlp_in_reg(const float* __restrict__ x, const float* __restrict__ W1,
                           const float* __restrict__ b1, const float* __restrict__ dinv,
                           float* __restrict__ hp, float* __restrict__ h0, int n) {
    __shared__ float part[MLPIN_NB * 256];   // [node][wv*64+f]
    int t = threadIdx.x;
    int f = t & 63, wv = t >> 6;
    float wreg[32];
#pragma unroll
    for (int kk = 0; kk < 32; kk++) wreg[kk] = W1[(32 * wv + kk) * HID + f];
    int ntiles = (n + MLPIN_NB - 1) / MLPIN_NB;
    for (int tile = blockIdx.x; tile < ntiles; tile += gridDim.x) {
        int node0 = tile * MLPIN_NB;
#pragma unroll
        for (int nn = 0; nn < MLPIN_NB; nn++) {
            int node = node0 + nn;
            float partial = 0.f;
            if (node < n) {
                const float4* xr = (const float4*)(x + (size_t)node * DIN + 32 * wv);
#pragma unroll
                for (int q = 0; q < 8; q++) {
                    float4 xv = xr[q];   // wave-broadcast load
                    partial += xv.x * wreg[4 * q] + xv.y * wreg[4 * q + 1] +
                               xv.z * wreg[4 * q + 2] + xv.w * wreg[4 * q + 3];
                }
            }
            part[nn * 256 + wv * 64 + f] = partial;
        }
        __syncthreads();
#pragma unroll
        for (int r = 0; r < (MLPIN_NB * 64) / 256; r++) {
            int idx = r * 256 + t;
            int nn = idx >> 6, f2 = idx & 63;
            int node = node0 + nn;
            if (node < n) {
                float s = part[nn * 256 + f2] + part[nn * 256 + 64 + f2] +
                          part[nn * 256 + 128 + f2] + part[nn * 256 + 192 + f2] + b1[f2];
                float val = fmaxf(s, 0.f);
                h0[(size_t)node * HID + f2] = val;
                hp[(size_t)node * HID + f2] = val * dinv[node];
            }
        }
        __syncthreads();
    }
}

// ---------- fused layer: agg -> blend h0 -> out@W -> relu -> (scaled) store ----------
// one wave per node (grid-stride); lane = feature; W column f in 64 VGPRs
__global__ void gcnii_layer(const float* __restrict__ hp, const float* __restrict__ h0,
                            const float* __restrict__ dinv,
                            const int* __restrict__ row_start, const int* __restrict__ cnt,
                            const int* __restrict__ csr_src,
                            const float* __restrict__ W, float beta, int scale_out,
                            float* __restrict__ hp_next, int n) {
    int f = threadIdx.x & 63;
    int wv = threadIdx.x >> 6;
    float wreg[64];
#pragma unroll
    for (int k = 0; k < 64; k++) wreg[k] = W[k * HID + f];   // coalesced; L2-hit
    int wid = blockIdx.x * 4 + wv;
    int nw = gridDim.x * 4;
    for (int v = wid; v < n; v += nw) {
        float dv = dinv[v];
        float acc = hp[(size_t)v * HID + f];    // self loop term (hp already has dinv[v])
        int j = row_start[v];
        int end = j + cnt[v];
        for (; j + 8 <= end; j += 8) {
            int s0 = csr_src[j],     s1 = csr_src[j + 1];
            int s2 = csr_src[j + 2], s3 = csr_src[j + 3];
            int s4 = csr_src[j + 4], s5 = csr_src[j + 5];
            int s6 = csr_src[j + 6], s7 = csr_src[j + 7];
            float a0 = hp[(size_t)s0 * HID + f];
            float a1 = hp[(size_t)s1 * HID + f];
            float a2 = hp[(size_t)s2 * HID + f];
            float a3 = hp[(size_t)s3 * HID + f];
            float a4 = hp[(size_t)s4 * HID + f];
            float a5 = hp[(size_t)s5 * HID + f];
            float a6 = hp[(size_t)s6 * HID + f];
            float a7 = hp[(size_t)s7 * HID + f];
            acc += ((a0 + a1) + (a2 + a3)) + ((a4 + a5) + (a6 + a7));
        }
        for (; j < end; ++j) acc += hp[(size_t)csr_src[j] * HID + f];
        float out = 0.9f * dv * acc + 0.1f * h0[(size_t)v * HID + f];
        float dot = 0.f;
#pragma unroll
        for (int k = 0; k < 64; k++) dot += __shfl(out, k) * wreg[k];
        float val = fmaxf((1.f - beta) * out + beta * dot, 0.f);
        hp_next[(size_t)v * HID + f] = scale_out ? dv * val : val;
    }
}

// ---------- y = h @ W2 + b2 ----------
__global__ void mlp_out(const float* __restrict__ h, const float* __restrict__ W2,
                        const float* __restrict__ b2, float* __restrict__ y, int n) {
    __shared__ float hs[32 * HID];        // 8 KB
    __shared__ float W2s[HID * DOUT];     // 10 KB
    __shared__ float b2s[DOUT];
    int t = threadIdx.x;
    for (int i = t; i < HID * DOUT; i += 256) W2s[i] = W2[i];
    if (t < DOUT) b2s[t] = b2[t];
    int node0 = blockIdx.x * 32;
    for (int i = t; i < 32 * HID; i += 256) {
        int node = node0 + (i >> 6);
        hs[i] = (node < n) ? h[(size_t)node0 * HID + i] : 0.f;
    }
    __syncthreads();
    for (int idx = t; idx < 32 * DOUT; idx += 256) {
        int nloc = idx / DOUT, fo = idx % DOUT;
        int node = node0 + nloc;
        if (node >= n) continue;
        float dot = b2s[fo];
#pragma unroll 8
        for (int k = 0; k < HID; k++) dot += hs[nloc * HID + k] * W2s[k * DOUT + fo];
        y[(size_t)node * DOUT + fo] = dot;
    }
}

extern "C" void kernel_launch(void* const* d_in, const int* in_sizes, int n_in,
                              void* d_out, int out_size, void* d_ws, size_t ws_size,
                              hipStream_t stream) {
    const float*    x     = (const float*)d_in[0];
    const uint32_t* ei    = (const uint32_t*)d_in[1];
    const float*    W1    = (const float*)d_in[2];
    const float*    b1    = (const float*)d_in[3];
    const float*    convw = (const float*)d_in[4];
    const float*    W2    = (const float*)d_in[5];
    const float*    b2    = (const float*)d_in[6];
    float*          y     = (float*)d_out;

    int N = in_sizes[0] / DIN;
    int E = in_sizes[1] / 2;

    char* ws = (char*)d_ws;
    size_t off = 0;
    auto alloc = [&](size_t bytes) -> char* {
        char* p = ws + off;
        off = (off + bytes + 255) & ~(size_t)255;
        return p;
    };
    int*   flag      = (int*)alloc(4);
    int*   cnt       = (int*)alloc((size_t)N * 4);
    int*   row_start = (int*)alloc((size_t)N * 4);
    int*   cursor    = (int*)alloc((size_t)N * 4);
    float* dinv      = (float*)alloc((size_t)N * 4);
    int*   blocksum  = (int*)alloc(512 * 4);
    int*   csr_src   = (int*)alloc((size_t)E * 4);
    float* h0        = (float*)alloc((size_t)N * HID * 4);
    float* hpA       = (float*)alloc((size_t)N * HID * 4);
    float* hpB       = (float*)alloc((size_t)N * HID * 4);

    detect_i64<<<1, 64, 0, stream>>>(ei, flag);
    init_cnt<<<cdiv(N, 256), 256, 0, stream>>>(cnt, N);
    count_deg<<<cdiv(E, 256), 256, 0, stream>>>(ei, flag, cnt, E);
    int nb = cdiv(N, 256);
    scan1<<<nb, 256, 0, stream>>>(cnt, row_start, blocksum, N);
    scan2<<<1, 512, 0, stream>>>(blocksum, nb);
    scan3<<<cdiv(N, 256), 256, 0, stream>>>(row_start, blocksum, cursor, N);
    compute_dinv<<<cdiv(N, 256), 256, 0, stream>>>(cnt, dinv, N);
    scatter_edges<<<cdiv(E, 256), 256, 0, stream>>>(ei, flag, row_start, cursor, csr_src, E);

    int mlpin_grid = min(1024, cdiv(N, MLPIN_NB));
    mlp_in_reg<<<mlpin_grid, 256, 0, stream>>>(x, W1, b1, dinv, hpA, h0, N);

    float* cur = hpA;
    float* nxt = hpB;
    for (int i = 0; i < N_LAYERS; i++) {
        float beta = logf(0.5f / (float)(i + 1) + 1.f);
        int scale_out = (i < N_LAYERS - 1) ? 1 : 0;   // last layer leaves h unscaled
        gcnii_layer<<<2048, 256, 0, stream>>>(cur, h0, dinv, row_start, cnt, csr_src,
                                              convw + (size_t)i * HID * HID, beta,
                                              scale_out, nxt, N);
        float* tmp = cur; cur = nxt; nxt = tmp;
    }
    mlp_out<<<cdiv(N, 32), 256, 0, stream>>>(cur, W2, b2, y, N);
}